// Round 1
// baseline (359.781 us; speedup 1.0000x reference)
//
#include <hip/hip_runtime.h>
#include <hip/hip_bf16.h>
#include <stdint.h>

#define HEADS 16
#define HD 64
#define SEQ 2048
#define BATCH 2
#define CDIM 1024
#define MROWS (BATCH*SEQ)   // 4096
#define K3C (3*CDIM)        // 3072
#define ATT_SCALE 0.125f

typedef __bf16 bf16x8 __attribute__((ext_vector_type(8)));
typedef float  f32x4  __attribute__((ext_vector_type(4)));

__device__ __forceinline__ unsigned short f2bf(float f) {
    __hip_bfloat16 h = __float2bfloat16(f);
    return __builtin_bit_cast(unsigned short, h);
}
__device__ __forceinline__ bf16x8 frag(uint4 u) { return __builtin_bit_cast(bf16x8, u); }

// async global->LDS, 16B per lane; lds base must be wave-uniform (lane*16 implicit)
__device__ __forceinline__ void async16(const unsigned short* g, unsigned short* lds) {
    __builtin_amdgcn_global_load_lds(
        (const __attribute__((address_space(1))) unsigned int*)g,
        (__attribute__((address_space(3))) unsigned int*)lds, 16, 0, 0);
}

// ---------------- cast / pack kernels ----------------

__global__ void cast_pack_A(const float* __restrict__ q, const float* __restrict__ k,
                            const float* __restrict__ v, unsigned short* __restrict__ A)
{
    const int m = blockIdx.x;       // 0..4095
    const int t = threadIdx.x;      // 0..255
    const float* srcs[3] = {q, k, v};
    #pragma unroll
    for (int i = 0; i < 3; ++i) {
        float4 f = *(const float4*)(srcs[i] + (size_t)m*CDIM + t*4);
        ushort4 s;
        s.x = f2bf(f.x); s.y = f2bf(f.y); s.z = f2bf(f.z); s.w = f2bf(f.w);
        *(ushort4*)(A + (size_t)m*K3C + i*CDIM + t*4) = s;
    }
}

__global__ void cast_w(const float* __restrict__ src, unsigned short* __restrict__ dst, int n4)
{
    int idx = blockIdx.x * blockDim.x + threadIdx.x;
    if (idx < n4) {
        float4 f = ((const float4*)src)[idx];
        ushort4 s;
        s.x = f2bf(f.x); s.y = f2bf(f.y); s.z = f2bf(f.z); s.w = f2bf(f.w);
        ((ushort4*)dst)[idx] = s;
    }
}

// ---------------- m97-style bf16 GEMM, C[m][n] = sum_k A[m][k]*B[n][k] ----------------
// EPI 0: qkv epilogue -> qh (x SCALE), kh as [BH][SEQ][64]; v transposed -> vt [BH][64][SEQ]
// EPI 1: proj epilogue -> out fp32 [M][N] + bias
template<int EPI>
__global__ __launch_bounds__(256, 2)
void gemm_bt(const unsigned short* __restrict__ A, const unsigned short* __restrict__ B,
             int M, int N, int K,
             unsigned short* __restrict__ qh, unsigned short* __restrict__ kh,
             unsigned short* __restrict__ vt,
             const float* __restrict__ bias, float* __restrict__ out)
{
    __shared__ __attribute__((aligned(16))) unsigned short As[128*32];
    __shared__ __attribute__((aligned(16))) unsigned short Bs[128*32];
    const int tid  = threadIdx.x;
    const int wave = tid >> 6;
    const int lane = tid & 63;
    const int l15  = lane & 15;
    const int quad = lane >> 4;
    const int wm = (wave >> 1) * 64;
    const int wn = (wave & 1) * 64;
    const int m0 = blockIdx.x * 128;
    const int n0 = blockIdx.y * 128;

    f32x4 acc[4][4] = {};

    const int srow = tid >> 2;
    const int sc8  = (tid & 3) * 8;

    for (int k0 = 0; k0 < K; k0 += 32) {
        #pragma unroll
        for (int t = 0; t < 2; ++t) {
            int row = t*64 + srow;
            const unsigned short* ga = A + (size_t)(m0 + row)*K + k0 + sc8;
            const unsigned short* gb = B + (size_t)(n0 + row)*K + k0 + sc8;
            async16(ga, &As[(t*256 + wave*64)*8]);
            async16(gb, &Bs[(t*256 + wave*64)*8]);
        }
        __syncthreads();
        uint4 af[4], bfv[4];
        #pragma unroll
        for (int i = 0; i < 4; ++i) {
            af[i]  = *(const uint4*)&As[(wm + i*16 + l15)*32 + quad*8];
            bfv[i] = *(const uint4*)&Bs[(wn + i*16 + l15)*32 + quad*8];
        }
        #pragma unroll
        for (int mi = 0; mi < 4; ++mi)
            #pragma unroll
            for (int ni = 0; ni < 4; ++ni)
                acc[mi][ni] = __builtin_amdgcn_mfma_f32_16x16x32_bf16(
                    frag(af[mi]), frag(bfv[ni]), acc[mi][ni], 0, 0, 0);
        __syncthreads();
    }

    if constexpr (EPI == 0) {
        #pragma unroll
        for (int mi = 0; mi < 4; ++mi) {
            int row0 = m0 + wm + mi*16 + quad*4;
            int b  = row0 >> 11;
            int nq = row0 & 2047;
            #pragma unroll
            for (int ni = 0; ni < 4; ++ni) {
                int col   = n0 + wn + ni*16 + l15;
                int which = col >> 10;
                int h     = (col >> 6) & 15;
                int d     = col & 63;
                int bh    = b*HEADS + h;
                if (which == 2) {
                    ushort4 pv;
                    pv.x = f2bf(acc[mi][ni][0]);
                    pv.y = f2bf(acc[mi][ni][1]);
                    pv.z = f2bf(acc[mi][ni][2]);
                    pv.w = f2bf(acc[mi][ni][3]);
                    *(ushort4*)&vt[((size_t)bh*HD + d)*SEQ + nq] = pv;
                } else {
                    unsigned short* dst = (which == 0) ? qh : kh;
                    float sc = (which == 0) ? ATT_SCALE : 1.0f;
                    #pragma unroll
                    for (int r = 0; r < 4; ++r)
                        dst[((size_t)bh*SEQ + nq + r)*HD + d] = f2bf(acc[mi][ni][r] * sc);
                }
            }
        }
    } else {
        #pragma unroll
        for (int mi = 0; mi < 4; ++mi) {
            int row0 = m0 + wm + mi*16 + quad*4;
            #pragma unroll
            for (int ni = 0; ni < 4; ++ni) {
                int col  = n0 + wn + ni*16 + l15;
                float bv = bias[col];
                #pragma unroll
                for (int r = 0; r < 4; ++r)
                    out[(size_t)(row0 + r)*N + col] = acc[mi][ni][r] + bv;
            }
        }
    }
}

// ---------------- flash attention ----------------
__global__ __launch_bounds__(256, 2)
void attention(const unsigned short* __restrict__ qh, const unsigned short* __restrict__ kh,
               const unsigned short* __restrict__ vt, unsigned short* __restrict__ xb)
{
    const int qt = blockIdx.x;
    const int h  = blockIdx.y;
    const int b  = blockIdx.z;
    const int bh = b*HEADS + h;
    const int tid  = threadIdx.x;
    const int wave = tid >> 6;
    const int lane = tid & 63;
    const int l15  = lane & 15;
    const int quad = lane >> 4;

    __shared__ __attribute__((aligned(16))) unsigned short Ks[64*72];
    __shared__ __attribute__((aligned(16))) unsigned short Vs[64*72];
    __shared__ __attribute__((aligned(16))) unsigned short Ps[4][16*72];

    const unsigned short* Qp = qh + ((size_t)bh*SEQ + qt*64)*HD;
    const unsigned short* Kp = kh + (size_t)bh*SEQ*HD;
    const unsigned short* Vp = vt + (size_t)bh*HD*SEQ;

    uint4 qf0 = *(const uint4*)(Qp + (size_t)(wave*16 + l15)*HD + quad*8);
    uint4 qf1 = *(const uint4*)(Qp + (size_t)(wave*16 + l15)*HD + 32 + quad*8);

    f32x4 o[4] = {};
    float m_r[4], l_r[4];
    #pragma unroll
    for (int r = 0; r < 4; ++r) { m_r[r] = -INFINITY; l_r[r] = 0.f; }

    for (int kt = 0; kt < SEQ/64; ++kt) {
        __syncthreads();
        #pragma unroll
        for (int t = 0; t < 2; ++t) {
            int rr = t*32 + (tid >> 3);
            int c8 = (tid & 7) * 8;
            *(uint4*)&Ks[rr*72 + c8] = *(const uint4*)(Kp + ((size_t)(kt*64 + rr))*HD + c8);
            *(uint4*)&Vs[rr*72 + c8] = *(const uint4*)(Vp + (size_t)rr*SEQ + kt*64 + c8);
        }
        __syncthreads();

        f32x4 s[4];
        #pragma unroll
        for (int st = 0; st < 4; ++st) {
            uint4 kf0 = *(const uint4*)&Ks[(st*16 + l15)*72 + quad*8];
            uint4 kf1 = *(const uint4*)&Ks[(st*16 + l15)*72 + 32 + quad*8];
            f32x4 z = {};
            z = __builtin_amdgcn_mfma_f32_16x16x32_bf16(frag(qf0), frag(kf0), z, 0, 0, 0);
            z = __builtin_amdgcn_mfma_f32_16x16x32_bf16(frag(qf1), frag(kf1), z, 0, 0, 0);
            s[st] = z;
        }

        float mloc[4], rs[4], al[4];
        #pragma unroll
        for (int r = 0; r < 4; ++r)
            mloc[r] = fmaxf(fmaxf(s[0][r], s[1][r]), fmaxf(s[2][r], s[3][r]));
        #pragma unroll
        for (int mask = 1; mask <= 8; mask <<= 1)
            #pragma unroll
            for (int r = 0; r < 4; ++r)
                mloc[r] = fmaxf(mloc[r], __shfl_xor(mloc[r], mask));

        float p[4][4];
        #pragma unroll
        for (int r = 0; r < 4; ++r) {
            float mn = fmaxf(m_r[r], mloc[r]);
            al[r] = __expf(m_r[r] - mn);
            m_r[r] = mn;
            float sum = 0.f;
            #pragma unroll
            for (int st = 0; st < 4; ++st) { p[st][r] = __expf(s[st][r] - mn); sum += p[st][r]; }
            rs[r] = sum;
        }
        #pragma unroll
        for (int mask = 1; mask <= 8; mask <<= 1)
            #pragma unroll
            for (int r = 0; r < 4; ++r)
                rs[r] += __shfl_xor(rs[r], mask);
        #pragma unroll
        for (int r = 0; r < 4; ++r) l_r[r] = al[r]*l_r[r] + rs[r];
        #pragma unroll
        for (int st = 0; st < 4; ++st)
            #pragma unroll
            for (int r = 0; r < 4; ++r)
                o[st][r] *= al[r];

        unsigned short* Pw = Ps[wave];
        #pragma unroll
        for (int st = 0; st < 4; ++st)
            #pragma unroll
            for (int r = 0; r < 4; ++r)
                Pw[(quad*4 + r)*72 + st*16 + l15] = f2bf(p[st][r]);
        asm volatile("s_waitcnt lgkmcnt(0)" ::: "memory");

        uint4 pf0 = *(const uint4*)&Pw[l15*72 + quad*8];
        uint4 pf1 = *(const uint4*)&Pw[l15*72 + 32 + quad*8];
        #pragma unroll
        for (int st = 0; st < 4; ++st) {
            uint4 vf0 = *(const uint4*)&Vs[(st*16 + l15)*72 + quad*8];
            uint4 vf1 = *(const uint4*)&Vs[(st*16 + l15)*72 + 32 + quad*8];
            o[st] = __builtin_amdgcn_mfma_f32_16x16x32_bf16(frag(pf0), frag(vf0), o[st], 0, 0, 0);
            o[st] = __builtin_amdgcn_mfma_f32_16x16x32_bf16(frag(pf1), frag(vf1), o[st], 0, 0, 0);
        }
    }

    const int mrow = b*SEQ + qt*64 + wave*16 + quad*4;
    #pragma unroll
    for (int r = 0; r < 4; ++r) {
        float inv = 1.0f / l_r[r];
        #pragma unroll
        for (int st = 0; st < 4; ++st)
            xb[(size_t)(mrow + r)*CDIM + h*HD + st*16 + l15] = f2bf(o[st][r] * inv);
    }
}

extern "C" void kernel_launch(void* const* d_in, const int* in_sizes, int n_in,
                              void* d_out, int out_size, void* d_ws, size_t ws_size,
                              hipStream_t stream)
{
    const float* q  = (const float*)d_in[0];
    const float* k  = (const float*)d_in[1];
    const float* v  = (const float*)d_in[2];
    const float* Wq = (const float*)d_in[3];
    const float* Wp = (const float*)d_in[4];
    const float* bp = (const float*)d_in[5];
    float* out = (float*)d_out;

    char* p = (char*)d_ws;
    auto carve = [&](size_t bytes) { char* r = p; p += (bytes + 255) & ~(size_t)255; return r; };
    unsigned short* Abuf   = (unsigned short*)carve((size_t)MROWS*K3C*2);
    unsigned short* Wqkvb  = (unsigned short*)carve((size_t)K3C*K3C*2);
    unsigned short* Wprojb = (unsigned short*)carve((size_t)CDIM*CDIM*2);
    unsigned short* qhb    = (unsigned short*)carve((size_t)BATCH*HEADS*SEQ*HD*2);
    unsigned short* khb    = (unsigned short*)carve((size_t)BATCH*HEADS*SEQ*HD*2);
    unsigned short* vtb    = (unsigned short*)carve((size_t)BATCH*HEADS*SEQ*HD*2);
    unsigned short* xbuf   = (unsigned short*)carve((size_t)MROWS*CDIM*2);

    cast_pack_A<<<MROWS, 256, 0, stream>>>(q, k, v, Abuf);
    cast_w<<<(K3C*K3C/4 + 255)/256, 256, 0, stream>>>(Wq, Wqkvb, K3C*K3C/4);
    cast_w<<<(CDIM*CDIM/4 + 255)/256, 256, 0, stream>>>(Wp, Wprojb, CDIM*CDIM/4);

    gemm_bt<0><<<dim3(MROWS/128, K3C/128), 256, 0, stream>>>(
        Abuf, Wqkvb, MROWS, K3C, K3C, qhb, khb, vtb, nullptr, nullptr);

    attention<<<dim3(SEQ/64, HEADS, BATCH), 256, 0, stream>>>(qhb, khb, vtb, xbuf);

    gemm_bt<1><<<dim3(MROWS/128, CDIM/128), 256, 0, stream>>>(
        xbuf, Wprojb, MROWS, CDIM, CDIM, nullptr, nullptr, nullptr, bp, out);
}

// Round 2
// 313.405 us; speedup vs baseline: 1.1480x; 1.1480x over previous
//
#include <hip/hip_runtime.h>
#include <hip/hip_bf16.h>
#include <stdint.h>

#define HEADS 16
#define HD 64
#define SEQ 2048
#define BATCH 2
#define CDIM 1024
#define MROWS (BATCH*SEQ)   // 4096
#define K3C (3*CDIM)        // 3072
#define ATT_SCALE 0.125f

typedef __bf16 bf16x8 __attribute__((ext_vector_type(8)));
typedef float  f32x4  __attribute__((ext_vector_type(4)));

__device__ __forceinline__ unsigned short f2bf(float f) {
    __hip_bfloat16 h = __float2bfloat16(f);
    return __builtin_bit_cast(unsigned short, h);
}
__device__ __forceinline__ unsigned int pack2bf(float a, float b) {
    return (unsigned int)f2bf(a) | ((unsigned int)f2bf(b) << 16);
}
__device__ __forceinline__ bf16x8 frag(uint4 u) { return __builtin_bit_cast(bf16x8, u); }

// async global->LDS, 16B per lane; lds base must be wave-uniform (lane*16 implicit)
__device__ __forceinline__ void async16(const unsigned short* g, unsigned short* lds) {
    __builtin_amdgcn_global_load_lds(
        (const __attribute__((address_space(1))) unsigned int*)g,
        (__attribute__((address_space(3))) unsigned int*)lds, 16, 0, 0);
}

// ---------------- cast / pack kernels ----------------

__global__ void cast_pack_A(const float* __restrict__ q, const float* __restrict__ k,
                            const float* __restrict__ v, unsigned short* __restrict__ A)
{
    const int m = blockIdx.x;
    const int t = threadIdx.x;
    const float* srcs[3] = {q, k, v};
    #pragma unroll
    for (int i = 0; i < 3; ++i) {
        float4 f = *(const float4*)(srcs[i] + (size_t)m*CDIM + t*4);
        ushort4 s;
        s.x = f2bf(f.x); s.y = f2bf(f.y); s.z = f2bf(f.z); s.w = f2bf(f.w);
        *(ushort4*)(A + (size_t)m*K3C + i*CDIM + t*4) = s;
    }
}

__global__ void cast_w(const float* __restrict__ src, unsigned short* __restrict__ dst, int n4)
{
    int idx = blockIdx.x * blockDim.x + threadIdx.x;
    if (idx < n4) {
        float4 f = ((const float4*)src)[idx];
        ushort4 s;
        s.x = f2bf(f.x); s.y = f2bf(f.y); s.z = f2bf(f.z); s.w = f2bf(f.w);
        ((ushort4*)dst)[idx] = s;
    }
}

// ---------------- m97-style bf16 GEMM, C[m][n] = sum_k A[m][k]*B[n][k] ----------------
template<int EPI>
__global__ __launch_bounds__(256, 2)
void gemm_bt(const unsigned short* __restrict__ A, const unsigned short* __restrict__ B,
             int M, int N, int K,
             unsigned short* __restrict__ qh, unsigned short* __restrict__ kh,
             unsigned short* __restrict__ vt,
             const float* __restrict__ bias, float* __restrict__ out)
{
    __shared__ __attribute__((aligned(16))) unsigned short As[128*32];
    __shared__ __attribute__((aligned(16))) unsigned short Bs[128*32];
    const int tid  = threadIdx.x;
    const int wave = tid >> 6;
    const int lane = tid & 63;
    const int l15  = lane & 15;
    const int quad = lane >> 4;
    const int wm = (wave >> 1) * 64;
    const int wn = (wave & 1) * 64;
    const int m0 = blockIdx.x * 128;
    const int n0 = blockIdx.y * 128;

    f32x4 acc[4][4] = {};

    const int srow = tid >> 2;
    const int sc8  = (tid & 3) * 8;

    for (int k0 = 0; k0 < K; k0 += 32) {
        #pragma unroll
        for (int t = 0; t < 2; ++t) {
            int row = t*64 + srow;
            const unsigned short* ga = A + (size_t)(m0 + row)*K + k0 + sc8;
            const unsigned short* gb = B + (size_t)(n0 + row)*K + k0 + sc8;
            async16(ga, &As[(t*256 + wave*64)*8]);
            async16(gb, &Bs[(t*256 + wave*64)*8]);
        }
        __syncthreads();
        uint4 af[4], bfv[4];
        #pragma unroll
        for (int i = 0; i < 4; ++i) {
            af[i]  = *(const uint4*)&As[(wm + i*16 + l15)*32 + quad*8];
            bfv[i] = *(const uint4*)&Bs[(wn + i*16 + l15)*32 + quad*8];
        }
        #pragma unroll
        for (int mi = 0; mi < 4; ++mi)
            #pragma unroll
            for (int ni = 0; ni < 4; ++ni)
                acc[mi][ni] = __builtin_amdgcn_mfma_f32_16x16x32_bf16(
                    frag(af[mi]), frag(bfv[ni]), acc[mi][ni], 0, 0, 0);
        __syncthreads();
    }

    if constexpr (EPI == 0) {
        #pragma unroll
        for (int mi = 0; mi < 4; ++mi) {
            int row0 = m0 + wm + mi*16 + quad*4;
            int b  = row0 >> 11;
            int nq = row0 & 2047;
            #pragma unroll
            for (int ni = 0; ni < 4; ++ni) {
                int col   = n0 + wn + ni*16 + l15;
                int which = col >> 10;
                int h     = (col >> 6) & 15;
                int d     = col & 63;
                int bh    = b*HEADS + h;
                if (which == 2) {
                    ushort4 pv;
                    pv.x = f2bf(acc[mi][ni][0]);
                    pv.y = f2bf(acc[mi][ni][1]);
                    pv.z = f2bf(acc[mi][ni][2]);
                    pv.w = f2bf(acc[mi][ni][3]);
                    *(ushort4*)&vt[((size_t)bh*HD + d)*SEQ + nq] = pv;
                } else {
                    unsigned short* dst = (which == 0) ? qh : kh;
                    float sc = (which == 0) ? ATT_SCALE : 1.0f;
                    #pragma unroll
                    for (int r = 0; r < 4; ++r)
                        dst[((size_t)bh*SEQ + nq + r)*HD + d] = f2bf(acc[mi][ni][r] * sc);
                }
            }
        }
    } else {
        #pragma unroll
        for (int mi = 0; mi < 4; ++mi) {
            int row0 = m0 + wm + mi*16 + quad*4;
            #pragma unroll
            for (int ni = 0; ni < 4; ++ni) {
                int col  = n0 + wn + ni*16 + l15;
                float bv = bias[col];
                #pragma unroll
                for (int r = 0; r < 4; ++r)
                    out[(size_t)(row0 + r)*N + col] = acc[mi][ni][r] + bv;
            }
        }
    }
}

// ---------------- flash attention, S^T formulation ----------------
// S^T = K·Q^T  (A=K-frag, B=Q-frag): C-layout puts key=quad*4+reg, q=l15 per lane.
// Softmax: within-lane over 16 keys + 2-round shfl (masks 16,32) over quads.
// P^T per lane = 4 consecutive keys for one q -> packed b64 LDS writes, b128 B-frag reads.
// PV: out^T = V^T·P^T (A=V^T from vt[d][key], B=P^T) -> o C-layout d=quad*4+reg, q=l15.
__global__ __launch_bounds__(256, 2)
void attention(const unsigned short* __restrict__ qh, const unsigned short* __restrict__ kh,
               const unsigned short* __restrict__ vt, unsigned short* __restrict__ xb)
{
    const int qt = blockIdx.x;
    const int h  = blockIdx.y;
    const int b  = blockIdx.z;
    const int bh = b*HEADS + h;
    const int tid  = threadIdx.x;
    const int wave = tid >> 6;
    const int lane = tid & 63;
    const int l15  = lane & 15;
    const int quad = lane >> 4;

    __shared__ __attribute__((aligned(16))) unsigned short Ks[64*72];
    __shared__ __attribute__((aligned(16))) unsigned short Vs[64*72];
    __shared__ __attribute__((aligned(16))) unsigned short Ps[4][16*72]; // per-wave P^T / O^T scratch

    const unsigned short* Qp = qh + ((size_t)bh*SEQ + qt*64)*HD;
    const unsigned short* Kp = kh + (size_t)bh*SEQ*HD;
    const unsigned short* Vp = vt + (size_t)bh*HD*SEQ;

    // Q B-frag (pre-scaled by 1/8): B[k=c][n=q]: lane l15=q, channels quad*8+j
    uint4 qf0 = *(const uint4*)(Qp + (size_t)(wave*16 + l15)*HD + quad*8);
    uint4 qf1 = *(const uint4*)(Qp + (size_t)(wave*16 + l15)*HD + 32 + quad*8);

    f32x4 o[4] = {};
    float m_s = -INFINITY, l_s = 0.f;

    unsigned short* Pl = Ps[wave];

    for (int kt = 0; kt < SEQ/64; ++kt) {
        __syncthreads();
        #pragma unroll
        for (int t = 0; t < 2; ++t) {
            int rr = t*32 + (tid >> 3);
            int c8 = (tid & 7) * 8;
            *(uint4*)&Ks[rr*72 + c8] = *(const uint4*)(Kp + ((size_t)(kt*64 + rr))*HD + c8);
            *(uint4*)&Vs[rr*72 + c8] = *(const uint4*)(Vp + (size_t)rr*SEQ + kt*64 + c8);
        }
        __syncthreads();

        // S^T tiles: s[st][r] = score(key = kt*64 + st*16 + quad*4 + r, q = l15)
        f32x4 s[4];
        #pragma unroll
        for (int st = 0; st < 4; ++st) {
            uint4 kf0 = *(const uint4*)&Ks[(st*16 + l15)*72 + quad*8];
            uint4 kf1 = *(const uint4*)&Ks[(st*16 + l15)*72 + 32 + quad*8];
            f32x4 z = {};
            z = __builtin_amdgcn_mfma_f32_16x16x32_bf16(frag(kf0), frag(qf0), z, 0, 0, 0);
            z = __builtin_amdgcn_mfma_f32_16x16x32_bf16(frag(kf1), frag(qf1), z, 0, 0, 0);
            s[st] = z;
        }

        // online softmax — one q per lane
        float mloc = s[0][0];
        #pragma unroll
        for (int st = 0; st < 4; ++st)
            #pragma unroll
            for (int r = 0; r < 4; ++r)
                mloc = fmaxf(mloc, s[st][r]);
        mloc = fmaxf(mloc, __shfl_xor(mloc, 16));
        mloc = fmaxf(mloc, __shfl_xor(mloc, 32));

        float mn = fmaxf(m_s, mloc);
        float al = __expf(m_s - mn);
        m_s = mn;

        float p[4][4];
        float rs = 0.f;
        #pragma unroll
        for (int st = 0; st < 4; ++st)
            #pragma unroll
            for (int r = 0; r < 4; ++r) { p[st][r] = __expf(s[st][r] - mn); rs += p[st][r]; }
        rs += __shfl_xor(rs, 16);
        rs += __shfl_xor(rs, 32);
        l_s = al*l_s + rs;

        #pragma unroll
        for (int st = 0; st < 4; ++st)
            #pragma unroll
            for (int r = 0; r < 4; ++r)
                o[st][r] *= al;

        // P^T -> LDS [q][key], packed b64 per subtile (4 consecutive keys)
        #pragma unroll
        for (int st = 0; st < 4; ++st) {
            uint2 pk;
            pk.x = pack2bf(p[st][0], p[st][1]);
            pk.y = pack2bf(p[st][2], p[st][3]);
            *(uint2*)&Pl[l15*72 + st*16 + quad*4] = pk;
        }
        asm volatile("s_waitcnt lgkmcnt(0)" ::: "memory");

        // B-frag of P^T: lane l15=q, keys quad*8+j
        uint4 pB0 = *(const uint4*)&Pl[l15*72 + quad*8];
        uint4 pB1 = *(const uint4*)&Pl[l15*72 + 32 + quad*8];

        #pragma unroll
        for (int st = 0; st < 4; ++st) {
            uint4 vf0 = *(const uint4*)&Vs[(st*16 + l15)*72 + quad*8];
            uint4 vf1 = *(const uint4*)&Vs[(st*16 + l15)*72 + 32 + quad*8];
            o[st] = __builtin_amdgcn_mfma_f32_16x16x32_bf16(frag(vf0), frag(pB0), o[st], 0, 0, 0);
            o[st] = __builtin_amdgcn_mfma_f32_16x16x32_bf16(frag(vf1), frag(pB1), o[st], 0, 0, 0);
        }
    }

    // epilogue: o holds out^T (d=st*16+quad*4+r, q=l15). Normalize, transpose via LDS,
    // then coalesced b128 stores.
    float inv = 1.0f / l_s;
    #pragma unroll
    for (int st = 0; st < 4; ++st) {
        uint2 pk;
        pk.x = pack2bf(o[st][0]*inv, o[st][1]*inv);
        pk.y = pack2bf(o[st][2]*inv, o[st][3]*inv);
        *(uint2*)&Pl[l15*72 + st*16 + quad*4] = pk;
    }
    asm volatile("s_waitcnt lgkmcnt(0)" ::: "memory");

    const int qr = lane >> 2;          // 0..15 query row within wave tile
    const int dd = (lane & 3) * 16;    // 0,16,32,48
    uint4 oa = *(const uint4*)&Pl[qr*72 + dd];
    uint4 ob = *(const uint4*)&Pl[qr*72 + dd + 8];
    const int mrow = b*SEQ + qt*64 + wave*16 + qr;
    *(uint4*)&xb[(size_t)mrow*CDIM + h*HD + dd]     = oa;
    *(uint4*)&xb[(size_t)mrow*CDIM + h*HD + dd + 8] = ob;
}

extern "C" void kernel_launch(void* const* d_in, const int* in_sizes, int n_in,
                              void* d_out, int out_size, void* d_ws, size_t ws_size,
                              hipStream_t stream)
{
    const float* q  = (const float*)d_in[0];
    const float* k  = (const float*)d_in[1];
    const float* v  = (const float*)d_in[2];
    const float* Wq = (const float*)d_in[3];
    const float* Wp = (const float*)d_in[4];
    const float* bp = (const float*)d_in[5];
    float* out = (float*)d_out;

    char* p = (char*)d_ws;
    auto carve = [&](size_t bytes) { char* r = p; p += (bytes + 255) & ~(size_t)255; return r; };
    unsigned short* Abuf   = (unsigned short*)carve((size_t)MROWS*K3C*2);
    unsigned short* Wqkvb  = (unsigned short*)carve((size_t)K3C*K3C*2);
    unsigned short* Wprojb = (unsigned short*)carve((size_t)CDIM*CDIM*2);
    unsigned short* qhb    = (unsigned short*)carve((size_t)BATCH*HEADS*SEQ*HD*2);
    unsigned short* khb    = (unsigned short*)carve((size_t)BATCH*HEADS*SEQ*HD*2);
    unsigned short* vtb    = (unsigned short*)carve((size_t)BATCH*HEADS*SEQ*HD*2);
    unsigned short* xbuf   = (unsigned short*)carve((size_t)MROWS*CDIM*2);

    cast_pack_A<<<MROWS, 256, 0, stream>>>(q, k, v, Abuf);
    cast_w<<<(K3C*K3C/4 + 255)/256, 256, 0, stream>>>(Wq, Wqkvb, K3C*K3C/4);
    cast_w<<<(CDIM*CDIM/4 + 255)/256, 256, 0, stream>>>(Wp, Wprojb, CDIM*CDIM/4);

    gemm_bt<0><<<dim3(MROWS/128, K3C/128), 256, 0, stream>>>(
        Abuf, Wqkvb, MROWS, K3C, K3C, qhb, khb, vtb, nullptr, nullptr);

    attention<<<dim3(SEQ/64, HEADS, BATCH), 256, 0, stream>>>(qhb, khb, vtb, xbuf);

    gemm_bt<1><<<dim3(MROWS/128, CDIM/128), 256, 0, stream>>>(
        xbuf, Wprojb, MROWS, CDIM, CDIM, nullptr, nullptr, nullptr, bp, out);
}